// Round 1
// baseline (512.384 us; speedup 1.0000x reference)
//
#include <hip/hip_runtime.h>

// Winograd F(2x2x2, 3x3x3) conv: N=4, Ci=Co=128, D=H=W=32, T=16 tiles/dim.
// 3-kernel pipeline: U transform -> V transform -> batched MFMA GEMM with
// fused inverse transform. bf16 operands, fp32 accumulation.

typedef short short8 __attribute__((ext_vector_type(8)));
typedef float f32x4 __attribute__((ext_vector_type(4)));

typedef __attribute__((address_space(1))) const void* gas_cvp;
typedef __attribute__((address_space(3))) void* las_vp;

__device__ __forceinline__ unsigned short f2bf(float f) {
  unsigned u = __float_as_uint(f);
  u += 0x7FFFu + ((u >> 16) & 1u);
  return (unsigned short)(u >> 16);
}

// ---------------- K1: weight transform ----------------
// U[abc][o][ci] bf16, abc = a*16 + b*4 + c
// G rows: g0=x0, g1=.5(x0+x1+x2), g2=.5(x0-x1+x2), g3=x2
__global__ void wt_kernel(const float* __restrict__ w, unsigned short* __restrict__ U) {
  int tid = blockIdx.x * 256 + threadIdx.x;  // 16384 threads
  int ci = tid & 127, o = tid >> 7;
  const float* wp = w + (size_t)(o * 128 + ci) * 27;
  float in[27];
#pragma unroll
  for (int j = 0; j < 27; ++j) in[j] = wp[j];
  float s1[4][9];
#pragma unroll
  for (int ef = 0; ef < 9; ++ef) {
    float x0 = in[ef], x1 = in[9 + ef], x2 = in[18 + ef];
    s1[0][ef] = x0;
    s1[1][ef] = 0.5f * (x0 + x1 + x2);
    s1[2][ef] = 0.5f * (x0 - x1 + x2);
    s1[3][ef] = x2;
  }
  float s2[4][4][3];
#pragma unroll
  for (int a = 0; a < 4; ++a)
#pragma unroll
    for (int f = 0; f < 3; ++f) {
      float x0 = s1[a][f], x1 = s1[a][3 + f], x2 = s1[a][6 + f];
      s2[a][0][f] = x0;
      s2[a][1][f] = 0.5f * (x0 + x1 + x2);
      s2[a][2][f] = 0.5f * (x0 - x1 + x2);
      s2[a][3][f] = x2;
    }
#pragma unroll
  for (int a = 0; a < 4; ++a)
#pragma unroll
    for (int b = 0; b < 4; ++b) {
      float x0 = s2[a][b][0], x1 = s2[a][b][1], x2 = s2[a][b][2];
      int base = ((a * 16 + b * 4) << 14) + o * 128 + ci;
      U[base + (0 << 14)] = f2bf(x0);
      U[base + (1 << 14)] = f2bf(0.5f * (x0 + x1 + x2));
      U[base + (2 << 14)] = f2bf(0.5f * (x0 - x1 + x2));
      U[base + (3 << 14)] = f2bf(x2);
    }
}

// ---------------- K2: input transform ----------------
// Block: 32 ci x 16 tiles (2 th x 8 tw), 512 threads.
// slab [32ci][4d][6h][18w] fp32 (stride 433/ci), then per-thread Bt^3,
// LDS transpose buffer Tb[64abc][16t][32ci] bf16, coalesced 16B stores.
// Bt rows: r0=x0-x2, r1=x1+x2, r2=x2-x1, r3=x1-x3
__global__ void vt_kernel(const float* __restrict__ x, unsigned short* __restrict__ V,
                          int n_base, int nt_slice) {
  __shared__ __align__(16) char smem_raw[65536];
  float* slab = (float*)smem_raw;                                      // 55424 B
  unsigned short(*Tb)[16][32] = (unsigned short(*)[16][32])smem_raw;   // 65536 B (after slab dead)

  int b = blockIdx.x;
  int cib = b & 3;
  int twb = (b >> 2) & 1;
  int thb = (b >> 3) & 7;
  int td = (b >> 6) & 15;
  int n_l = b >> 10;
  int n = n_base + n_l;
  int CI0 = cib * 32;
  int d0 = td * 2 - 1, h0 = thb * 4 - 1, w0 = twb * 16 - 1;

  for (int i = threadIdx.x; i < 32 * 432; i += 512) {
    int ci = i / 432, r = i - ci * 432;
    int dd = r / 108, r2 = r - dd * 108;
    int hh = r2 / 18, ww = r2 - hh * 18;
    int dg = d0 + dd, hg = h0 + hh, wg = w0 + ww;
    float v = 0.0f;
    if ((unsigned)dg < 32u && (unsigned)hg < 32u && (unsigned)wg < 32u)
      v = x[((size_t)((n * 128 + CI0 + ci) * 32 + dg) * 32 + hg) * 32 + wg];
    slab[ci * 433 + dd * 108 + hh * 18 + ww] = v;
  }
  __syncthreads();

  int ci = threadIdx.x & 31, tl = threadIdx.x >> 5;  // tl: 0..15
  int tw = tl & 7, thl = tl >> 3;
  const float* sp = slab + ci * 433 + (2 * thl) * 18 + 2 * tw;
  float s3v[64];
  {
    float in[4][4][4];
#pragma unroll
    for (int fd = 0; fd < 4; ++fd)
#pragma unroll
      for (int fh = 0; fh < 4; ++fh)
#pragma unroll
        for (int fw = 0; fw < 4; ++fw)
          in[fd][fh][fw] = sp[fd * 108 + fh * 18 + fw];
    float s1[4][4][4];  // [a][fh][fw]
#pragma unroll
    for (int fh = 0; fh < 4; ++fh)
#pragma unroll
      for (int fw = 0; fw < 4; ++fw) {
        float x0 = in[0][fh][fw], x1 = in[1][fh][fw], x2 = in[2][fh][fw], x3 = in[3][fh][fw];
        s1[0][fh][fw] = x0 - x2;
        s1[1][fh][fw] = x1 + x2;
        s1[2][fh][fw] = x2 - x1;
        s1[3][fh][fw] = x1 - x3;
      }
    float s2[4][4][4];  // [a][b][fw]
#pragma unroll
    for (int a = 0; a < 4; ++a)
#pragma unroll
      for (int fw = 0; fw < 4; ++fw) {
        float x0 = s1[a][0][fw], x1 = s1[a][1][fw], x2 = s1[a][2][fw], x3 = s1[a][3][fw];
        s2[a][0][fw] = x0 - x2;
        s2[a][1][fw] = x1 + x2;
        s2[a][2][fw] = x2 - x1;
        s2[a][3][fw] = x1 - x3;
      }
#pragma unroll
    for (int a = 0; a < 4; ++a)
#pragma unroll
      for (int bb = 0; bb < 4; ++bb) {
        float x0 = s2[a][bb][0], x1 = s2[a][bb][1], x2 = s2[a][bb][2], x3 = s2[a][bb][3];
        s3v[(a * 4 + bb) * 4 + 0] = x0 - x2;
        s3v[(a * 4 + bb) * 4 + 1] = x1 + x2;
        s3v[(a * 4 + bb) * 4 + 2] = x2 - x1;
        s3v[(a * 4 + bb) * 4 + 3] = x1 - x3;
      }
  }
  __syncthreads();  // slab no longer needed; reuse as Tb
#pragma unroll
  for (int idx = 0; idx < 64; ++idx) Tb[idx][tl][ci] = f2bf(s3v[idx]);
  __syncthreads();

  int tg_base = n_l * 4096 + td * 256 + (thb * 2) * 16 + twb * 8;  // slice-local tile idx
#pragma unroll
  for (int rnd = 0; rnd < 8; ++rnd) {
    int abc = rnd * 8 + (threadIdx.x >> 6);
    int i = threadIdx.x & 63;
    int t = i >> 2, c8 = (i & 3) * 8;
    uint4 val = *(const uint4*)&Tb[abc][t][c8];
    int tg = tg_base + (t >> 3) * 16 + (t & 7);
    unsigned short* dst = V + ((size_t)abc * nt_slice + tg) * 128 + CI0 + c8;
    *(uint4*)dst = val;
  }
}

// ---------------- K3: batched GEMM + fused inverse transform ----------------
// Block: 128 o x 64 t, 8 waves (one 16-o slice each, 4 t-frags of 16).
// Per abc: stage V[abc][64t][128ci] (16 KB) via global_load_lds (dbuf, swizzled
// global source / linear LDS dest), 4 MFMA k-steps, accumulate M full-K, then
// epilogue: P0/P1 (At over a, compile-time), Y += (At[l,b]*At[m,c]) * Pk.
__global__ __launch_bounds__(512, 2) void wg_gemm(const unsigned short* __restrict__ U,
                                                  const unsigned short* __restrict__ V,
                                                  float* __restrict__ y, int n_base,
                                                  int nt_slice) {
  __shared__ __align__(16) unsigned short vbuf[2][64 * 128];  // 2 x 16 KB
  const int tid = threadIdx.x;
  const int lane = tid & 63;
  const int wid = tid >> 6;
  const int tb = blockIdx.x * 64;  // slice-local tile base
  const int o_wb = wid * 16;
  const int lo = lane & 15;  // A-row (o) / B-col (t) index within frag
  const int hi = lane >> 4;  // k-group

  const f32x4 zf = {0.f, 0.f, 0.f, 0.f};
  f32x4 Y[2][2][2][4];
#pragma unroll
  for (int k = 0; k < 2; ++k)
#pragma unroll
    for (int l = 0; l < 2; ++l)
#pragma unroll
      for (int m = 0; m < 2; ++m)
#pragma unroll
        for (int f = 0; f < 4; ++f) Y[k][l][m][f] = zf;

  auto stage = [&](int i_next) {
    int a = i_next & 3, bcn = i_next >> 2;
    int abc = a * 16 + bcn;
    const char* src = (const char*)(V + ((size_t)abc * nt_slice + tb) * 128);
    char* dstbase = (char*)&vbuf[i_next & 1][0];
#pragma unroll
    for (int it = 0; it < 2; ++it) {
      int L = (tid + it * 512) * 16;  // byte offset in 16 KB tile
      int t = L >> 8;
      int bo = L & 255;
      int sb = bo ^ ((t & 7) << 4);  // inverse-swizzled global source
      __builtin_amdgcn_global_load_lds((gas_cvp)(src + t * 256 + sb), (las_vp)(dstbase + L), 16,
                                       0, 0);
    }
  };

  stage(0);
  __syncthreads();

  for (int bc = 0; bc < 16; ++bc) {
    f32x4 P0[4], P1[4];
#pragma unroll
    for (int f = 0; f < 4; ++f) {
      P0[f] = zf;
      P1[f] = zf;
    }
#pragma unroll
    for (int a = 0; a < 4; ++a) {
      int i = bc * 4 + a;
      if (i < 63) stage(i + 1);
      const unsigned short* ub = U + ((size_t)(a * 16 + bc) << 14) + (o_wb + lo) * 128 + hi * 8;
      const char* vb = (const char*)&vbuf[i & 1][0];
      f32x4 M[4];
#pragma unroll
      for (int ks = 0; ks < 4; ++ks) {
        short8 A = *(const short8*)(ub + ks * 32);
#pragma unroll
        for (int f = 0; f < 4; ++f) {
          int t = f * 16 + lo;
          int boff = (t * 256 + (ks * 32 + hi * 8) * 2) ^ ((t & 7) << 4);
          short8 B = *(const short8*)(vb + boff);
          if (ks == 0)
            M[f] = __builtin_amdgcn_mfma_f32_16x16x32_bf16(A, B, zf, 0, 0, 0);
          else
            M[f] = __builtin_amdgcn_mfma_f32_16x16x32_bf16(A, B, M[f], 0, 0, 0);
        }
      }
      // At rows: [1,1,1,0] and [0,1,-1,-1]
#pragma unroll
      for (int f = 0; f < 4; ++f) {
        if (a == 0) {
          P0[f] += M[f];
        } else if (a == 1) {
          P0[f] += M[f];
          P1[f] += M[f];
        } else if (a == 2) {
          P0[f] += M[f];
          P1[f] -= M[f];
        } else {
          P1[f] -= M[f];
        }
      }
      __syncthreads();
    }
    int bq = bc >> 2, cq = bc & 3;
    float cl0 = (bq == 3) ? 0.f : 1.f;
    float cl1 = (bq == 0) ? 0.f : ((bq == 1) ? 1.f : -1.f);
    float cm0 = (cq == 3) ? 0.f : 1.f;
    float cm1 = (cq == 0) ? 0.f : ((cq == 1) ? 1.f : -1.f);
    float c00 = cl0 * cm0, c01 = cl0 * cm1, c10 = cl1 * cm0, c11 = cl1 * cm1;
#pragma unroll
    for (int f = 0; f < 4; ++f) {
      Y[0][0][0][f] += c00 * P0[f];
      Y[0][0][1][f] += c01 * P0[f];
      Y[0][1][0][f] += c10 * P0[f];
      Y[0][1][1][f] += c11 * P0[f];
      Y[1][0][0][f] += c00 * P1[f];
      Y[1][0][1][f] += c01 * P1[f];
      Y[1][1][0][f] += c10 * P1[f];
      Y[1][1][1][f] += c11 * P1[f];
    }
  }

  // write out: element (o, t): o = o_wb + hi*4 + q; t_local = f*16 + lo
#pragma unroll
  for (int f = 0; f < 4; ++f) {
    int t_local = f * 16 + lo;
    int tg = tb + t_local;
    int n = n_base + (tg >> 12);
    int rem = tg & 4095;
    int td = rem >> 8, th = (rem >> 4) & 15, tw = rem & 15;
#pragma unroll
    for (int q = 0; q < 4; ++q) {
      int o = o_wb + hi * 4 + q;
      float* pb = y + (size_t)(n * 128 + o) * 32768 + 2 * tw;
#pragma unroll
      for (int k = 0; k < 2; ++k)
#pragma unroll
        for (int l = 0; l < 2; ++l) {
          float* p = pb + (2 * td + k) * 1024 + (2 * th + l) * 32;
          *(float2*)p = make_float2(Y[k][l][0][f][q], Y[k][l][1][f][q]);
        }
    }
  }
}

extern "C" void kernel_launch(void* const* d_in, const int* in_sizes, int n_in, void* d_out,
                              int out_size, void* d_ws, size_t ws_size, hipStream_t stream) {
  const float* x = (const float*)d_in[0];
  const float* w = (const float*)d_in[1];
  float* y = (float*)d_out;
  char* ws = (char*)d_ws;
  unsigned short* U = (unsigned short*)ws;
  unsigned short* V = (unsigned short*)(ws + (4ull << 20));
  const size_t per_img = 64ull * 4096 * 128 * 2;  // 64 MiB of V per image
  int n_s = 1;
  if (ws_size >= (4ull << 20) + 4 * per_img)
    n_s = 4;
  else if (ws_size >= (4ull << 20) + 2 * per_img)
    n_s = 2;

  wt_kernel<<<64, 256, 0, stream>>>(w, U);
  for (int nb = 0; nb < 4; nb += n_s) {
    int nt_slice = 4096 * n_s;
    vt_kernel<<<dim3(1024 * n_s), 512, 0, stream>>>(x, V, nb, nt_slice);
    wg_gemm<<<dim3(64 * n_s), 512, 0, stream>>>(U, V, y, nb, nt_slice);
  }
}

// Round 2
// 468.363 us; speedup vs baseline: 1.0940x; 1.0940x over previous
//
#include <hip/hip_runtime.h>

// Winograd F(2x2x2, 3x3x3) conv: N=4, Ci=Co=128, D=H=W=32, T=16 tiles/dim.
// K1: weight transform into MFMA-fragment-ordered U2.
// K2: input transform -> V[abc][t][ci] bf16 (swizzle-ready rows).
// K3: 64 batched GEMMs with fused inverse transform; counted-vmcnt pipeline
//     (depth 2), V staged via global_load_lds ring, U prefetched to regs.

typedef short short8 __attribute__((ext_vector_type(8)));
typedef float f32x4 __attribute__((ext_vector_type(4)));

typedef __attribute__((address_space(1))) const void* gas_cvp;
typedef __attribute__((address_space(3))) void* las_vp;

__device__ __forceinline__ unsigned short f2bf(float f) {
  unsigned u = __float_as_uint(f);
  u += 0x7FFFu + ((u >> 16) & 1u);
  return (unsigned short)(u >> 16);
}

// ---------------- K1: weight transform ----------------
// U2 element for (abc, o, ci) lives at
//   abc*16384 + ((g*4 + ks)*64 + hi*16 + lo)*8 + j
// with g=o>>4, lo=o&15, ks=ci>>5, hi=(ci>>3)&3, j=ci&7 -- so a wave's A-frag
// load (lane = hi*16+lo, 16B x 4ks) is fully coalesced (1KB/instr).
__global__ void wt_kernel(const float* __restrict__ w, unsigned short* __restrict__ U) {
  int tid = blockIdx.x * 256 + threadIdx.x;  // 16384 threads
  int ci = tid & 127, o = tid >> 7;
  int g = o >> 4, lo = o & 15, ks = ci >> 5, hi = (ci >> 3) & 3, jj = ci & 7;
  int base2 = ((g * 4 + ks) * 64 + hi * 16 + lo) * 8 + jj;
  const float* wp = w + (size_t)(o * 128 + ci) * 27;
  float in[27];
#pragma unroll
  for (int j = 0; j < 27; ++j) in[j] = wp[j];
  float s1[4][9];
#pragma unroll
  for (int ef = 0; ef < 9; ++ef) {
    float x0 = in[ef], x1 = in[9 + ef], x2 = in[18 + ef];
    s1[0][ef] = x0;
    s1[1][ef] = 0.5f * (x0 + x1 + x2);
    s1[2][ef] = 0.5f * (x0 - x1 + x2);
    s1[3][ef] = x2;
  }
  float s2[4][4][3];
#pragma unroll
  for (int a = 0; a < 4; ++a)
#pragma unroll
    for (int f = 0; f < 3; ++f) {
      float x0 = s1[a][f], x1 = s1[a][3 + f], x2 = s1[a][6 + f];
      s2[a][0][f] = x0;
      s2[a][1][f] = 0.5f * (x0 + x1 + x2);
      s2[a][2][f] = 0.5f * (x0 - x1 + x2);
      s2[a][3][f] = x2;
    }
#pragma unroll
  for (int a = 0; a < 4; ++a)
#pragma unroll
    for (int b = 0; b < 4; ++b) {
      float x0 = s2[a][b][0], x1 = s2[a][b][1], x2 = s2[a][b][2];
      size_t ab = (size_t)(a * 16 + b * 4) * 16384 + base2;
      U[ab + 0 * 16384] = f2bf(x0);
      U[ab + 1 * 16384] = f2bf(0.5f * (x0 + x1 + x2));
      U[ab + 2 * 16384] = f2bf(0.5f * (x0 - x1 + x2));
      U[ab + 3 * 16384] = f2bf(x2);
    }
}

// ---------------- K2: input transform ----------------
__global__ void vt_kernel(const float* __restrict__ x, unsigned short* __restrict__ V,
                          int n_base, int nt_slice) {
  __shared__ __align__(16) char smem_raw[65536];
  float* slab = (float*)smem_raw;
  unsigned short(*Tb)[16][32] = (unsigned short(*)[16][32])smem_raw;

  int b = blockIdx.x;
  int cib = b & 3;
  int twb = (b >> 2) & 1;
  int thb = (b >> 3) & 7;
  int td = (b >> 6) & 15;
  int n_l = b >> 10;
  int n = n_base + n_l;
  int CI0 = cib * 32;
  int d0 = td * 2 - 1, h0 = thb * 4 - 1, w0 = twb * 16 - 1;

  for (int i = threadIdx.x; i < 32 * 432; i += 512) {
    int ci = i / 432, r = i - ci * 432;
    int dd = r / 108, r2 = r - dd * 108;
    int hh = r2 / 18, ww = r2 - hh * 18;
    int dg = d0 + dd, hg = h0 + hh, wg = w0 + ww;
    float v = 0.0f;
    if ((unsigned)dg < 32u && (unsigned)hg < 32u && (unsigned)wg < 32u)
      v = x[((size_t)((n * 128 + CI0 + ci) * 32 + dg) * 32 + hg) * 32 + wg];
    slab[ci * 433 + dd * 108 + hh * 18 + ww] = v;
  }
  __syncthreads();

  int ci = threadIdx.x & 31, tl = threadIdx.x >> 5;
  int tw = tl & 7, thl = tl >> 3;
  const float* sp = slab + ci * 433 + (2 * thl) * 18 + 2 * tw;
  float s3v[64];
  {
    float in[4][4][4];
#pragma unroll
    for (int fd = 0; fd < 4; ++fd)
#pragma unroll
      for (int fh = 0; fh < 4; ++fh)
#pragma unroll
        for (int fw = 0; fw < 4; ++fw)
          in[fd][fh][fw] = sp[fd * 108 + fh * 18 + fw];
    float s1[4][4][4];
#pragma unroll
    for (int fh = 0; fh < 4; ++fh)
#pragma unroll
      for (int fw = 0; fw < 4; ++fw) {
        float x0 = in[0][fh][fw], x1 = in[1][fh][fw], x2 = in[2][fh][fw], x3 = in[3][fh][fw];
        s1[0][fh][fw] = x0 - x2;
        s1[1][fh][fw] = x1 + x2;
        s1[2][fh][fw] = x2 - x1;
        s1[3][fh][fw] = x1 - x3;
      }
    float s2[4][4][4];
#pragma unroll
    for (int a = 0; a < 4; ++a)
#pragma unroll
      for (int fw = 0; fw < 4; ++fw) {
        float x0 = s1[a][0][fw], x1 = s1[a][1][fw], x2 = s1[a][2][fw], x3 = s1[a][3][fw];
        s2[a][0][fw] = x0 - x2;
        s2[a][1][fw] = x1 + x2;
        s2[a][2][fw] = x2 - x1;
        s2[a][3][fw] = x1 - x3;
      }
#pragma unroll
    for (int a = 0; a < 4; ++a)
#pragma unroll
      for (int bb = 0; bb < 4; ++bb) {
        float x0 = s2[a][bb][0], x1 = s2[a][bb][1], x2 = s2[a][bb][2], x3 = s2[a][bb][3];
        s3v[(a * 4 + bb) * 4 + 0] = x0 - x2;
        s3v[(a * 4 + bb) * 4 + 1] = x1 + x2;
        s3v[(a * 4 + bb) * 4 + 2] = x2 - x1;
        s3v[(a * 4 + bb) * 4 + 3] = x1 - x3;
      }
  }
  __syncthreads();
#pragma unroll
  for (int idx = 0; idx < 64; ++idx) Tb[idx][tl][ci] = f2bf(s3v[idx]);
  __syncthreads();

  int tg_base = n_l * 4096 + td * 256 + (thb * 2) * 16 + twb * 8;
#pragma unroll
  for (int rnd = 0; rnd < 8; ++rnd) {
    int abc = rnd * 8 + (threadIdx.x >> 6);
    int i = threadIdx.x & 63;
    int t = i >> 2, c8 = (i & 3) * 8;
    uint4 val = *(const uint4*)&Tb[abc][t][c8];
    int tg = tg_base + (t >> 3) * 16 + (t & 7);
    unsigned short* dst = V + ((size_t)abc * nt_slice + tg) * 128 + CI0 + c8;
    *(uint4*)dst = val;
  }
}

// ---------------- K3: batched GEMM + fused inverse transform ----------------
// Grid: img x 4 o-groups(32o) x 128 t-blocks(32t). Block 128 thr = 2 waves,
// each wave 16o x 32t. V staged in 4-deep LDS ring (8KB tiles) via
// global_load_lds (linear dest, inverse-swizzled source); U prefetched into
// rotating registers at the same depth so the per-wave vmcnt stream stays
// uniform: per iter 4 V-lds + 4 U loads -> steady-state s_waitcnt vmcnt(12)
// + raw s_barrier (never drain to 0 in the loop).
__global__ __launch_bounds__(128, 3) void wg_gemm(const unsigned short* __restrict__ U,
                                                  const unsigned short* __restrict__ V,
                                                  float* __restrict__ y, int n_base,
                                                  int nt_slice) {
  __shared__ __align__(16) unsigned short vbuf[4][32 * 128];  // 4 x 8 KB
  const int tid = threadIdx.x;
  const int lane = tid & 63;
  const int wid = tid >> 6;  // 0..1
  const int b = blockIdx.x;
  const int img = b >> 9;
  const int og = (b >> 7) & 3;
  const int tblk = b & 127;
  const int tb = img * 4096 + tblk * 32;  // slice-local tile base
  const int g = og * 2 + wid;             // o-16-group
  const int lo = lane & 15;
  const int hi = lane >> 4;

  const unsigned short* Ug = U + (size_t)g * 2048 + (size_t)lane * 8;

  const f32x4 zf = {0.f, 0.f, 0.f, 0.f};
  f32x4 Y[2][2][2][2];  // [f][k][l][m]
#pragma unroll
  for (int f = 0; f < 2; ++f)
#pragma unroll
    for (int k = 0; k < 2; ++k)
#pragma unroll
      for (int l = 0; l < 2; ++l)
#pragma unroll
        for (int m = 0; m < 2; ++m) Y[f][k][l][m] = zf;
  f32x4 P0[2], P1[2];
  short8 ua[2][4];

  auto stageV = [&](int i) {
    int a = i & 3, bc = i >> 2;
    int abc = a * 16 + bc;
    const char* src = (const char*)(V + ((size_t)abc * nt_slice + tb) * 128);
    char* dstb = (char*)&vbuf[i & 3][0];
#pragma unroll
    for (int it = 0; it < 4; ++it) {
      int L = (tid + it * 128) * 16;
      int t = L >> 8, bo = L & 255;
      int sb = bo ^ ((t & 7) << 4);  // inverse-swizzled global source
      __builtin_amdgcn_global_load_lds((gas_cvp)(src + t * 256 + sb), (las_vp)(dstb + L), 16, 0,
                                       0);
    }
  };
  auto loadU = [&](int i, short8* dst) {
    int a = i & 3, bc = i >> 2;
    int abc = a * 16 + bc;
    const unsigned short* up = Ug + (size_t)abc * 16384;
#pragma unroll
    for (int ks = 0; ks < 4; ++ks) dst[ks] = *(const short8*)(up + ks * 512);
  };

  // prologue: 2 tiles in flight
  stageV(0);
  loadU(0, ua[0]);
  stageV(1);
  loadU(1, ua[1]);

  for (int j4 = 0; j4 < 64; j4 += 4) {
    int bc = j4 >> 2;
#pragma unroll
    for (int p = 0; p < 4; ++p) {
      int i = j4 + p;
      if (i < 62) stageV(i + 2);
      if (i < 62)
        asm volatile("s_waitcnt vmcnt(12)" ::: "memory");
      else if (i == 62)
        asm volatile("s_waitcnt vmcnt(8)" ::: "memory");
      else
        asm volatile("s_waitcnt vmcnt(0)" ::: "memory");
      __builtin_amdgcn_s_barrier();
      const char* vb = (const char*)&vbuf[p][0];  // i & 3 == p
      f32x4 M[2];
#pragma unroll
      for (int ks = 0; ks < 4; ++ks) {
#pragma unroll
        for (int f = 0; f < 2; ++f) {
          int t = f * 16 + lo;
          int boff = (t * 256 + ks * 64 + hi * 16) ^ ((t & 7) << 4);
          short8 Bf = *(const short8*)(vb + boff);
          M[f] = __builtin_amdgcn_mfma_f32_16x16x32_bf16(ua[p & 1][ks], Bf,
                                                         (ks == 0) ? zf : M[f], 0, 0, 0);
        }
      }
      // At rows: [1,1,1,0], [0,1,-1,-1]; a == p
#pragma unroll
      for (int f = 0; f < 2; ++f) {
        if (p == 0) {
          P0[f] = M[f];
          P1[f] = zf;
        } else if (p == 1) {
          P0[f] += M[f];
          P1[f] = M[f];
        } else if (p == 2) {
          P0[f] += M[f];
          P1[f] -= M[f];
        } else {
          P1[f] -= M[f];
        }
      }
      if (i < 62) loadU(i + 2, ua[p & 1]);
    }
    int bq = bc >> 2, cq = bc & 3;
    float cl0 = (bq == 3) ? 0.f : 1.f;
    float cl1 = (bq == 0) ? 0.f : ((bq == 1) ? 1.f : -1.f);
    float cm0 = (cq == 3) ? 0.f : 1.f;
    float cm1 = (cq == 0) ? 0.f : ((cq == 1) ? 1.f : -1.f);
    float c00 = cl0 * cm0, c01 = cl0 * cm1, c10 = cl1 * cm0, c11 = cl1 * cm1;
#pragma unroll
    for (int f = 0; f < 2; ++f) {
      Y[f][0][0][0] += c00 * P0[f];
      Y[f][0][0][1] += c01 * P0[f];
      Y[f][0][1][0] += c10 * P0[f];
      Y[f][0][1][1] += c11 * P0[f];
      Y[f][1][0][0] += c00 * P1[f];
      Y[f][1][0][1] += c01 * P1[f];
      Y[f][1][1][0] += c10 * P1[f];
      Y[f][1][1][1] += c11 * P1[f];
    }
  }

  // write out: o = g*16 + hi*4 + q; t = tb + f*16 + lo
#pragma unroll
  for (int f = 0; f < 2; ++f) {
    int tg = tb + f * 16 + lo;
    int n = n_base + (tg >> 12);
    int rem = tg & 4095;
    int td = rem >> 8, th = (rem >> 4) & 15, tw = rem & 15;
#pragma unroll
    for (int q = 0; q < 4; ++q) {
      int o = g * 16 + hi * 4 + q;
      float* pb = y + (size_t)(n * 128 + o) * 32768 + 2 * tw;
#pragma unroll
      for (int k = 0; k < 2; ++k)
#pragma unroll
        for (int l = 0; l < 2; ++l) {
          float* p = pb + (2 * td + k) * 1024 + (2 * th + l) * 32;
          *(float2*)p = make_float2(Y[f][k][l][0][q], Y[f][k][l][1][q]);
        }
    }
  }
}

extern "C" void kernel_launch(void* const* d_in, const int* in_sizes, int n_in, void* d_out,
                              int out_size, void* d_ws, size_t ws_size, hipStream_t stream) {
  const float* x = (const float*)d_in[0];
  const float* w = (const float*)d_in[1];
  float* y = (float*)d_out;
  char* ws = (char*)d_ws;
  unsigned short* U = (unsigned short*)ws;
  unsigned short* V = (unsigned short*)(ws + (4ull << 20));
  const size_t per_img = 64ull * 4096 * 128 * 2;  // 64 MiB of V per image
  int n_s = 1;
  if (ws_size >= (4ull << 20) + 4 * per_img)
    n_s = 4;
  else if (ws_size >= (4ull << 20) + 2 * per_img)
    n_s = 2;

  wt_kernel<<<64, 256, 0, stream>>>(w, U);
  for (int nb = 0; nb < 4; nb += n_s) {
    int nt_slice = 4096 * n_s;
    vt_kernel<<<dim3(1024 * n_s), 512, 0, stream>>>(x, V, nb, nt_slice);
    wg_gemm<<<dim3(512 * n_s), 128, 0, stream>>>(U, V, y, nb, nt_slice);
  }
}